// Round 6
// baseline (245.517 us; speedup 1.0000x reference)
//
#include <hip/hip_runtime.h>
#include <hip/hip_bf16.h>
#include <stdint.h>

// Shapes (fixed by the problem)
#define B_  16
#define M_  2048            // T*N
#define C_  256
#define BM_ 32768           // B_*M_

typedef __bf16 bf16x8 __attribute__((ext_vector_type(8)));
typedef __bf16 bf16x2 __attribute__((ext_vector_type(2)));
typedef float  f32x4  __attribute__((ext_vector_type(4)));
typedef float  f32x16 __attribute__((ext_vector_type(16)));
typedef unsigned int uint2v __attribute__((ext_vector_type(2)));

__device__ __forceinline__ unsigned short f2bf(float f) {
    uint32_t u = __builtin_bit_cast(uint32_t, f);
    u += 0x7fffu + ((u >> 16) & 1u);          // RNE
    return (unsigned short)(u >> 16);
}

__device__ __forceinline__ uint32_t pkbf(float a, float b) {
    bf16x2 t; t[0] = (__bf16)a; t[1] = (__bf16)b;   // compiler -> v_cvt_pk_bf16_f32
    return __builtin_bit_cast(uint32_t, t);
}

// ---------------------------------------------------------------- kernel 1
// adjT5 = 5*log2(e) * adj^T (logits in exp2 domain); affwB = bf16(affine_w)
__global__ void prep_weights(const float* __restrict__ adj,
                             const float* __restrict__ affw,
                             unsigned short* __restrict__ adjT5,
                             unsigned short* __restrict__ affwB) {
    int idx = blockIdx.x * 256 + threadIdx.x;   // 0..65535
    int d = idx >> 8, c = idx & 255;
    adjT5[d * 256 + c] = f2bf(7.2134752f * adj[c * 256 + d]);
    affwB[idx] = f2bf(affw[idx]);
}

// ---------------------------------------------------------------- kernel 2
__global__ void l2norm_kernel(const float* __restrict__ x,
                              unsigned short* __restrict__ nf,
                              float* __restrict__ norms) {
    int w = threadIdx.x >> 6, lane = threadIdx.x & 63;
    int row = blockIdx.x * 4 + w;
    const float4 v = *reinterpret_cast<const float4*>(x + (size_t)row * 256 + lane * 4);
    float ss = v.x * v.x + v.y * v.y + v.z * v.z + v.w * v.w;
    #pragma unroll
    for (int m = 1; m < 64; m <<= 1) ss += __shfl_xor(ss, m);
    float nrm = sqrtf(ss);
    float s = 1.0f / fmaxf(nrm, 1e-12f);
    ushort4 o;
    o.x = f2bf(v.x * s); o.y = f2bf(v.y * s); o.z = f2bf(v.z * s); o.w = f2bf(v.w * s);
    *reinterpret_cast<ushort4*>(nf + (size_t)row * 256 + lane * 4) = o;
    if (lane == 0) norms[row] = nrm;
}

// ---------------------------------------------------------------- kernel 3
// One pass over nf producing BOTH Q = nf@adjT5 (row-major) and
// V2 = norms*(nf@affw)+bias, stored KV-BLOCKED: V2[kv/32][c][kv%32] so the
// flash kernel's per-step V tile is one contiguous 16KB slab (L2-friendly).
__global__ __launch_bounds__(512, 2)
void dual_gemm(const unsigned short* __restrict__ A,
               const unsigned short* __restrict__ B1,
               const unsigned short* __restrict__ B2,
               const float* __restrict__ norms,
               const float* __restrict__ bias,
               unsigned short* __restrict__ outQ,
               unsigned short* __restrict__ outV2) {
    __shared__ unsigned short bb1[256 * 56];
    __shared__ unsigned short bb2[256 * 56];
    int tid = threadIdx.x;
    int w = tid >> 6, lane = tid & 63, g = lane >> 4, r = lane & 15;
    int m0 = blockIdx.x * 128;

    const f32x4 z = {0.f, 0.f, 0.f, 0.f};
    f32x4 accq[16], accv[16];
    #pragma unroll
    for (int i = 0; i < 16; i++) { accq[i] = z; accv[i] = z; }

    for (int dc = 0; dc < 8; dc++) {
        __syncthreads();
        #pragma unroll
        for (int it = 0; it < 2; it++) {
            int n = (w * 2 + it) * 16 + (lane >> 2);
            int t = lane & 3;
            *reinterpret_cast<uint4*>(&bb1[n * 56 + t * 8]) =
                *reinterpret_cast<const uint4*>(B1 + (size_t)n * 256 + dc * 32 + t * 8);
            *reinterpret_cast<uint4*>(&bb2[n * 56 + t * 8]) =
                *reinterpret_cast<const uint4*>(B2 + (size_t)n * 256 + dc * 32 + t * 8);
        }
        __syncthreads();
        bf16x8 af = *reinterpret_cast<const bf16x8*>(
            A + (size_t)(m0 + w * 16 + r) * 256 + dc * 32 + g * 8);
        #pragma unroll
        for (int nf16 = 0; nf16 < 16; nf16++) {
            bf16x8 b1f = *reinterpret_cast<const bf16x8*>(&bb1[(nf16 * 16 + r) * 56 + g * 8]);
            accq[nf16] = __builtin_amdgcn_mfma_f32_16x16x32_bf16(af, b1f, accq[nf16], 0, 0, 0);
            bf16x8 b2f = *reinterpret_cast<const bf16x8*>(&bb2[(nf16 * 16 + r) * 56 + g * 8]);
            accv[nf16] = __builtin_amdgcn_mfma_f32_16x16x32_bf16(af, b2f, accv[nf16], 0, 0, 0);
        }
    }
    // Q epilogue: row-major
    #pragma unroll
    for (int nf16 = 0; nf16 < 16; nf16++) {
        int n = nf16 * 16 + r;
        #pragma unroll
        for (int j = 0; j < 4; j++) {
            int m = m0 + w * 16 + g * 4 + j;
            outQ[(size_t)m * 256 + n] = f2bf(accq[nf16][j]);
        }
    }
    // V epilogue: kv-blocked [kv/32][c][kv%32], * norms + bias
    int mm = m0 + w * 16 + g * 4;               // kv row of acc elem j=0
    int kvb = mm >> 5, j0 = mm & 31;            // j0..j0+3 within one 32-block
    float4 nr = *reinterpret_cast<const float4*>(norms + mm);
    #pragma unroll
    for (int nf16 = 0; nf16 < 16; nf16++) {
        int n = nf16 * 16 + r;
        float bv = bias[n];
        ushort4 o;
        o.x = f2bf(accv[nf16][0] * nr.x + bv);
        o.y = f2bf(accv[nf16][1] * nr.y + bv);
        o.z = f2bf(accv[nf16][2] * nr.z + bv);
        o.w = f2bf(accv[nf16][3] * nr.w + bv);
        *reinterpret_cast<ushort4*>(outV2 + (size_t)kvb * 8192 + n * 32 + j0) = o;
    }
}

// ---------------------------------------------------------------- kernel 4
// Flash v6: NO staging, NO main-loop barriers. K/V are L2-resident (XCD-
// pinned batches), so each wave free-runs: 512 thr = 4 q-subblocks x 2
// kv-halves; wave = 32 q rows, 32 steps of 32 kv, operands read directly
// from global (K row-major, V kv-blocked) with imm-offset dwordx4 loads.
// Waves de-phase naturally -> MFMA/VALU/VMEM overlap without lockstep.
// LDS only for the final kv-half merge (one barrier) + fused LN/LeakyReLU.
__global__ __launch_bounds__(512, 2)
void flash_kernel(const unsigned short* __restrict__ Q,
                  const unsigned short* __restrict__ K,
                  const unsigned short* __restrict__ V2,
                  const float* __restrict__ gam,
                  const float* __restrict__ bet,
                  float* __restrict__ out) {
    __shared__ __align__(16) char smem[135168];
    const int tid = threadIdx.x;
    const int w = tid >> 6, lane = tid & 63;
    const int wg = w & 3, h = w >> 2;           // q sub-block, kv half
    const int hl = lane >> 5, m = lane & 31;    // lane half, lane-in-half
    const int blk = blockIdx.x;
    const int b = (blk & 7) * 2 + (blk >> 7);   // XCD-pinned batch
    const int mblk = (blk >> 3) & 15;
    const int q0 = b * M_ + mblk * 128 + wg * 32;

    // Q fragments: B-operand; lane holds Q[q0+m][ch*16 + hl*8 ..+8]
    bf16x8 qf[16];
    #pragma unroll
    for (int ch = 0; ch < 16; ch++)
        qf[ch] = *reinterpret_cast<const bf16x8*>(
            Q + (size_t)(q0 + m) * 256 + ch * 16 + hl * 8);

    const f32x16 z16 = {0,0,0,0, 0,0,0,0, 0,0,0,0, 0,0,0,0};
    f32x16 acc[8];
    #pragma unroll
    for (int cb = 0; cb < 8; cb++) acc[cb] = z16;
    float mmax = 0.0f, lsum = 0.0f;             // exp2 domain

    // per-thread streaming pointers
    const unsigned short* Kp = K + (size_t)(b * M_ + h * 1024 + m) * 256 + hl * 8;
    const unsigned short* Vp = V2 + (size_t)(b * 64 + h * 32) * 8192 + m * 32 + hl * 8;

    for (int step = 0; step < 32; step++) {
        // ---- S^T[32 kv][32 q] = K . Q^T  (K frags direct from L2)
        f32x16 sf = z16;
        __builtin_amdgcn_s_setprio(1);
        #pragma unroll
        for (int ch = 0; ch < 16; ch++) {
            bf16x8 kf = *reinterpret_cast<const bf16x8*>(Kp + ch * 16);
            sf = __builtin_amdgcn_mfma_f32_32x32x16_bf16(kf, qf[ch], sf, 0, 0, 0);
        }
        __builtin_amdgcn_s_setprio(0);

        // ---- online softmax (exp2 domain), defer-max THR=11
        float tm = sf[0];
        #pragma unroll
        for (int i = 1; i < 16; i++) tm = fmaxf(tm, sf[i]);
        tm = fmaxf(tm, __shfl_xor(tm, 32));
        if (__any(tm > mmax + 11.0f)) {
            float mn = fmaxf(mmax, tm);
            float corr = exp2f(mmax - mn);
            lsum *= corr;
            #pragma unroll
            for (int cb = 0; cb < 8; cb++) acc[cb] *= corr;
            mmax = mn;
        }
        #pragma unroll
        for (int i = 0; i < 16; i++) {
            sf[i] = exp2f(sf[i] - mmax);
            lsum += sf[i];
        }
        // pack P; lane holds P[q=m][kv=(reg&3)+8*(reg>>2)+4*hl]
        uint32_t pk0 = pkbf(sf[0], sf[1]),   pk1 = pkbf(sf[2], sf[3]);
        uint32_t pk2 = pkbf(sf[4], sf[5]),   pk3 = pkbf(sf[6], sf[7]);
        uint32_t pk4 = pkbf(sf[8], sf[9]),   pk5 = pkbf(sf[10], sf[11]);
        uint32_t pk6 = pkbf(sf[12], sf[13]), pk7 = pkbf(sf[14], sf[15]);
        uint2v r0 = __builtin_amdgcn_permlane32_swap(pk0, pk2, false, false);
        uint2v r1 = __builtin_amdgcn_permlane32_swap(pk1, pk3, false, false);
        uint2v r2 = __builtin_amdgcn_permlane32_swap(pk4, pk6, false, false);
        uint2v r3 = __builtin_amdgcn_permlane32_swap(pk5, pk7, false, false);
        uint4 u0; u0.x = r0[0]; u0.y = r1[0]; u0.z = r0[1]; u0.w = r1[1];
        uint4 u1; u1.x = r2[0]; u1.y = r3[0]; u1.z = r2[1]; u1.w = r3[1];
        bf16x8 pf0 = __builtin_bit_cast(bf16x8, u0);   // P^T[kv 0..15][q]
        bf16x8 pf1 = __builtin_bit_cast(bf16x8, u1);   // P^T[kv 16..31][q]

        // ---- out^T[c][q] += V . P^T  (V frags direct from L2, blocked tile)
        __builtin_amdgcn_s_setprio(1);
        #pragma unroll
        for (int cb = 0; cb < 8; cb++) {
            const unsigned short* vp = Vp + (size_t)cb * 1024;
            bf16x8 v0 = *reinterpret_cast<const bf16x8*>(vp);
            acc[cb] = __builtin_amdgcn_mfma_f32_32x32x16_bf16(v0, pf0, acc[cb], 0, 0, 0);
            bf16x8 v1 = *reinterpret_cast<const bf16x8*>(vp + 16);
            acc[cb] = __builtin_amdgcn_mfma_f32_32x32x16_bf16(v1, pf1, acc[cb], 0, 0, 0);
        }
        __builtin_amdgcn_s_setprio(0);

        Kp += 32 * 256;      // next 32 kv rows
        Vp += 8192;          // next kv-blocked tile
    }

    // ---- cross-half lsum (per q-row total for this wave's kv half)
    lsum += __shfl_xor(lsum, 32);

    // ---- kv-half merge through LDS (only LDS/barrier use in the kernel)
    float* mp  = (float*)smem;
    float* mlp = (float*)(smem + 133120);
    if (h == 1) {
        #pragma unroll
        for (int cb = 0; cb < 8; cb++)
            #pragma unroll
            for (int q4 = 0; q4 < 4; q4++) {
                float4 v;
                v.x = acc[cb][q4 * 4 + 0]; v.y = acc[cb][q4 * 4 + 1];
                v.z = acc[cb][q4 * 4 + 2]; v.w = acc[cb][q4 * 4 + 3];
                *reinterpret_cast<float4*>(
                    mp + wg * 8320 + m * 260 + cb * 32 + q4 * 8 + 4 * hl) = v;
            }
        if (hl == 0) {
            float2 ml; ml.x = mmax; ml.y = lsum;
            *reinterpret_cast<float2*>(mlp + (wg * 32 + m) * 2) = ml;
        }
    }
    __syncthreads();
    if (h == 0) {
        float2 ml1 = *reinterpret_cast<const float2*>(mlp + (wg * 32 + m) * 2);
        float mn = fmaxf(mmax, ml1.x);
        float c0 = exp2f(mmax - mn), c1 = exp2f(ml1.x - mn);
        lsum = lsum * c0 + ml1.y * c1;
        #pragma unroll
        for (int cb = 0; cb < 8; cb++)
            #pragma unroll
            for (int q4 = 0; q4 < 4; q4++) {
                float4 a1 = *reinterpret_cast<const float4*>(
                    mp + wg * 8320 + m * 260 + cb * 32 + q4 * 8 + 4 * hl);
                acc[cb][q4 * 4 + 0] = acc[cb][q4 * 4 + 0] * c0 + a1.x * c1;
                acc[cb][q4 * 4 + 1] = acc[cb][q4 * 4 + 1] * c0 + a1.y * c1;
                acc[cb][q4 * 4 + 2] = acc[cb][q4 * 4 + 2] * c0 + a1.z * c1;
                acc[cb][q4 * 4 + 3] = acc[cb][q4 * 4 + 3] * c0 + a1.w * c1;
            }
        // ---- fused LayerNorm + LeakyReLU; lane holds 128 of 256 channels
        float inv = 1.0f / lsum;
        float s = 0.0f, ssq = 0.0f;
        #pragma unroll
        for (int cb = 0; cb < 8; cb++)
            #pragma unroll
            for (int i = 0; i < 16; i++) {
                float v = acc[cb][i] * inv;
                acc[cb][i] = v;
                s += v; ssq += v * v;
            }
        s   += __shfl_xor(s, 32);
        ssq += __shfl_xor(ssq, 32);
        float mu = s * (1.0f / 256.0f);
        float var = ssq * (1.0f / 256.0f) - mu * mu;
        float rstd = rsqrtf(var + 1e-5f);
        size_t rowoff = (size_t)(q0 + m) * 256;
        #pragma unroll
        for (int cb = 0; cb < 8; cb++)
            #pragma unroll
            for (int q4 = 0; q4 < 4; q4++) {
                int c0i = cb * 32 + q4 * 8 + 4 * hl;
                float4 gg = *reinterpret_cast<const float4*>(gam + c0i);
                float4 bb = *reinterpret_cast<const float4*>(bet + c0i);
                float4 o;
                o.x = (acc[cb][q4 * 4 + 0] - mu) * rstd * gg.x + bb.x;
                o.y = (acc[cb][q4 * 4 + 1] - mu) * rstd * gg.y + bb.y;
                o.z = (acc[cb][q4 * 4 + 2] - mu) * rstd * gg.z + bb.z;
                o.w = (acc[cb][q4 * 4 + 3] - mu) * rstd * gg.w + bb.w;
                o.x = o.x >= 0.f ? o.x : 0.01f * o.x;
                o.y = o.y >= 0.f ? o.y : 0.01f * o.y;
                o.z = o.z >= 0.f ? o.z : 0.01f * o.z;
                o.w = o.w >= 0.f ? o.w : 0.01f * o.w;
                *reinterpret_cast<float4*>(out + rowoff + c0i) = o;
            }
    }
}

// ---------------------------------------------------------------- launcher
extern "C" void kernel_launch(void* const* d_in, const int* in_sizes, int n_in,
                              void* d_out, int out_size, void* d_ws, size_t ws_size,
                              hipStream_t stream) {
    const float* local_feat = (const float*)d_in[0];
    const float* adj_w    = (const float*)d_in[3];
    const float* affine_w = (const float*)d_in[4];
    const float* affine_b = (const float*)d_in[5];
    const float* ln_g     = (const float*)d_in[6];
    const float* ln_b     = (const float*)d_in[7];
    float* out = (float*)d_out;

    char* ws = (char*)d_ws;
    unsigned short* nf    = (unsigned short*)(ws);                 // 16 MiB
    unsigned short* q     = (unsigned short*)(ws + 16777216);      // 16 MiB
    unsigned short* v2    = (unsigned short*)(ws + 33554432);      // 16 MiB
    float*          norms = (float*)         (ws + 50331648);      // 128 KiB
    unsigned short* adjT5 = (unsigned short*)(ws + 50462720);      // 128 KiB
    unsigned short* affw  = (unsigned short*)(ws + 50593792);      // 128 KiB

    prep_weights<<<256, 256, 0, stream>>>(adj_w, affine_w, adjT5, affw);
    l2norm_kernel<<<BM_ / 4, 256, 0, stream>>>(local_feat, nf, norms);
    dual_gemm<<<BM_ / 128, 512, 0, stream>>>(nf, adjT5, affw, norms, affine_b, q, v2);
    flash_kernel<<<256, 512, 0, stream>>>(q, nf, v2, ln_g, ln_b, out);
}

// Round 7
// 192.728 us; speedup vs baseline: 1.2739x; 1.2739x over previous
//
#include <hip/hip_runtime.h>
#include <hip/hip_bf16.h>
#include <stdint.h>

// Shapes (fixed by the problem)
#define B_  16
#define M_  2048            // T*N
#define C_  256
#define BM_ 32768           // B_*M_

typedef __bf16 bf16x8 __attribute__((ext_vector_type(8)));
typedef __bf16 bf16x2 __attribute__((ext_vector_type(2)));
typedef float  f32x4  __attribute__((ext_vector_type(4)));
typedef float  f32x16 __attribute__((ext_vector_type(16)));
typedef unsigned int uint2v __attribute__((ext_vector_type(2)));

__device__ __forceinline__ unsigned short f2bf(float f) {
    uint32_t u = __builtin_bit_cast(uint32_t, f);
    u += 0x7fffu + ((u >> 16) & 1u);          // RNE
    return (unsigned short)(u >> 16);
}

__device__ __forceinline__ uint32_t pkbf(float a, float b) {
    bf16x2 t; t[0] = (__bf16)a; t[1] = (__bf16)b;   // compiler -> v_cvt_pk_bf16_f32
    return __builtin_bit_cast(uint32_t, t);
}

__device__ __forceinline__ float bf2f(unsigned short u) {
    return __builtin_bit_cast(float, ((uint32_t)u) << 16);
}

// async global->LDS, 16B/lane; LDS dest = wave-uniform base, HW adds lane*16
__device__ __forceinline__ void gload16(const void* g, void* l) {
    __builtin_amdgcn_global_load_lds(
        (const __attribute__((address_space(1))) void*)g,
        (__attribute__((address_space(3))) void*)l, 16, 0, 0);
}

// Explicit LDS-DMA publish: drain vmcnt BEFORE the barrier, fence scheduler.
__device__ __forceinline__ void publish_barrier() {
    asm volatile("s_waitcnt vmcnt(0)" ::: "memory");
    __builtin_amdgcn_sched_barrier(0);
    __syncthreads();
    __builtin_amdgcn_sched_barrier(0);
}

// ---------------------------------------------------------------- kernel 1
// adjT5 = 5*log2(e) * adj^T (logits in exp2 domain); affwB = bf16(affine_w)
__global__ void prep_weights(const float* __restrict__ adj,
                             const float* __restrict__ affw,
                             unsigned short* __restrict__ adjT5,
                             unsigned short* __restrict__ affwB) {
    int idx = blockIdx.x * 256 + threadIdx.x;   // 0..65535
    int d = idx >> 8, c = idx & 255;
    adjT5[d * 256 + c] = f2bf(7.2134752f * adj[c * 256 + d]);
    affwB[idx] = f2bf(affw[idx]);
}

// ---------------------------------------------------------------- kernel 2
__global__ void l2norm_kernel(const float* __restrict__ x,
                              unsigned short* __restrict__ nf,
                              float* __restrict__ norms) {
    int w = threadIdx.x >> 6, lane = threadIdx.x & 63;
    int row = blockIdx.x * 4 + w;
    const float4 v = *reinterpret_cast<const float4*>(x + (size_t)row * 256 + lane * 4);
    float ss = v.x * v.x + v.y * v.y + v.z * v.z + v.w * v.w;
    #pragma unroll
    for (int m = 1; m < 64; m <<= 1) ss += __shfl_xor(ss, m);
    float nrm = sqrtf(ss);
    float s = 1.0f / fmaxf(nrm, 1e-12f);
    ushort4 o;
    o.x = f2bf(v.x * s); o.y = f2bf(v.y * s); o.z = f2bf(v.z * s); o.w = f2bf(v.w * s);
    *reinterpret_cast<ushort4*>(nf + (size_t)row * 256 + lane * 4) = o;
    if (lane == 0) norms[row] = nrm;
}

// ---------------------------------------------------------------- kernel 3
// One pass over nf producing BOTH Q = nf@adjT5 (row-major) and
// Vt = norms*(nf@affw)+bias (transposed [256][BM]).
__global__ __launch_bounds__(512, 2)
void dual_gemm(const unsigned short* __restrict__ A,
               const unsigned short* __restrict__ B1,
               const unsigned short* __restrict__ B2,
               const float* __restrict__ norms,
               const float* __restrict__ bias,
               unsigned short* __restrict__ outQ,
               unsigned short* __restrict__ outT) {
    __shared__ unsigned short bb1[256 * 56];
    __shared__ unsigned short bb2[256 * 56];
    int tid = threadIdx.x;
    int w = tid >> 6, lane = tid & 63, g = lane >> 4, r = lane & 15;
    int m0 = blockIdx.x * 128;

    const f32x4 z = {0.f, 0.f, 0.f, 0.f};
    f32x4 accq[16], accv[16];
    #pragma unroll
    for (int i = 0; i < 16; i++) { accq[i] = z; accv[i] = z; }

    for (int dc = 0; dc < 8; dc++) {
        __syncthreads();
        #pragma unroll
        for (int it = 0; it < 2; it++) {
            int n = (w * 2 + it) * 16 + (lane >> 2);
            int t = lane & 3;
            *reinterpret_cast<uint4*>(&bb1[n * 56 + t * 8]) =
                *reinterpret_cast<const uint4*>(B1 + (size_t)n * 256 + dc * 32 + t * 8);
            *reinterpret_cast<uint4*>(&bb2[n * 56 + t * 8]) =
                *reinterpret_cast<const uint4*>(B2 + (size_t)n * 256 + dc * 32 + t * 8);
        }
        __syncthreads();
        bf16x8 af = *reinterpret_cast<const bf16x8*>(
            A + (size_t)(m0 + w * 16 + r) * 256 + dc * 32 + g * 8);
        #pragma unroll
        for (int nf16 = 0; nf16 < 16; nf16++) {
            bf16x8 b1f = *reinterpret_cast<const bf16x8*>(&bb1[(nf16 * 16 + r) * 56 + g * 8]);
            accq[nf16] = __builtin_amdgcn_mfma_f32_16x16x32_bf16(af, b1f, accq[nf16], 0, 0, 0);
            bf16x8 b2f = *reinterpret_cast<const bf16x8*>(&bb2[(nf16 * 16 + r) * 56 + g * 8]);
            accv[nf16] = __builtin_amdgcn_mfma_f32_16x16x32_bf16(af, b2f, accv[nf16], 0, 0, 0);
        }
    }
    // Q epilogue: row-major
    #pragma unroll
    for (int nf16 = 0; nf16 < 16; nf16++) {
        int n = nf16 * 16 + r;
        #pragma unroll
        for (int j = 0; j < 4; j++) {
            int m = m0 + w * 16 + g * 4 + j;
            outQ[(size_t)m * 256 + n] = f2bf(accq[nf16][j]);
        }
    }
    // V epilogue: transposed, * norms + bias
    float4 nr = *reinterpret_cast<const float4*>(norms + m0 + w * 16 + g * 4);
    #pragma unroll
    for (int nf16 = 0; nf16 < 16; nf16++) {
        int n = nf16 * 16 + r;
        float bv = bias[n];
        ushort4 o;
        o.x = f2bf(accv[nf16][0] * nr.x + bv);
        o.y = f2bf(accv[nf16][1] * nr.y + bv);
        o.z = f2bf(accv[nf16][2] * nr.z + bv);
        o.w = f2bf(accv[nf16][3] * nr.w + bv);
        *reinterpret_cast<ushort4*>(outT + (size_t)n * BM_ + m0 + w * 16 + g * 4) = o;
    }
}

// ---------------------------------------------------------------- kernel 4
// Flash v7: 512 blocks of 256 thr (4 waves x 32q), each block owns ONE kv
// HALF (h = 0/1) -> 2 independent blocks/CU de-phase naturally (no shared
// barriers between them). K/V double-buffered via global_load_lds (r5's
// verified swizzle patterns), one publish_barrier per step AFTER PV, then
// stage(step+2) into the just-consumed buffers. h=0 writes normalized f32 O
// to out; h=1 writes normalized bf16 partial + per-row weight; merge kernel
// combines + LN + LeakyReLU.
// LDS 64KB: K0@0 K1@16K | V0@32K V1@48K.
__global__ __launch_bounds__(256, 2)
void flash_kernel(const unsigned short* __restrict__ Q,
                  const unsigned short* __restrict__ K,
                  const unsigned short* __restrict__ Vt,
                  float* __restrict__ out,
                  unsigned short* __restrict__ part1,
                  float* __restrict__ ml) {
    __shared__ __align__(16) char smem[65536];
    const int tid = threadIdx.x;
    const int w = tid >> 6, lane = tid & 63;
    const int hl = lane >> 5, m = lane & 31;    // lane half, lane-in-half
    const int blk = blockIdx.x;
    const int xcd = blk & 7, idx = blk >> 3;    // batch pinned to XCD
    const int b = xcd * 2 + (idx >> 5);
    const int sub = idx & 31;
    const int mblk = sub >> 1, h = sub & 1;     // q-tile, kv half
    const int q0 = b * M_ + mblk * 128 + w * 32;
    const int kvbase = b * M_ + h * 1024;

    // Q fragments: B-operand; lane holds Q[q0+m][ch*16 + hl*8 ..+8]
    bf16x8 qf[16];
    #pragma unroll
    for (int ch = 0; ch < 16; ch++)
        qf[ch] = *reinterpret_cast<const bf16x8*>(
            Q + (size_t)(q0 + m) * 256 + ch * 16 + hl * 8);

    const f32x16 z16 = {0,0,0,0, 0,0,0,0, 0,0,0,0, 0,0,0,0};
    f32x16 acc[8];
    #pragma unroll
    for (int cb = 0; cb < 8; cb++) acc[cb] = z16;
    float mmax = 0.0f, lsum = 0.0f;             // exp2 domain

    const unsigned short* Kb = K + (size_t)kvbase * 256;

    auto stageK = [&](int step, int buf) {
        char* kb = smem + buf * 16384;
        #pragma unroll
        for (int it = 0; it < 4; it++) {
            int s = it * 256 + tid;
            int n = s >> 5, t = s & 31;
            gload16(Kb + (size_t)(step * 32 + n) * 256 + ((t ^ (n & 7)) * 8),
                    kb + (it * 256 + w * 64) * 16);
        }
    };
    auto stageV = [&](int step, int buf) {
        char* vb = smem + 32768 + buf * 16384;
        #pragma unroll
        for (int it = 0; it < 4; it++) {
            int s = it * 256 + tid;
            int c = ((s >> 5) << 3) + (s & 7);  // slot -> (c, j) decode
            int j = (s >> 3) & 3;
            gload16(Vt + (size_t)c * BM_ + kvbase + step * 32 + j * 8,
                    vb + (it * 256 + w * 64) * 16);
        }
    };

    stageK(0, 0); stageV(0, 0);
    publish_barrier();
    stageK(1, 1); stageV(1, 1);

    #pragma unroll 2
    for (int step = 0; step < 32; step++) {
        const int cur = step & 1;
        char* kb = smem + cur * 16384;
        char* vb = smem + 32768 + cur * 16384;

        // ---- S^T[32 kv][32 q] = K . Q^T
        f32x16 sf = z16;
        __builtin_amdgcn_s_setprio(1);
        #pragma unroll
        for (int ch = 0; ch < 16; ch++) {
            int slot = (ch * 2 + hl) ^ (m & 7);
            bf16x8 kf = *reinterpret_cast<const bf16x8*>(kb + m * 512 + slot * 16);
            sf = __builtin_amdgcn_mfma_f32_32x32x16_bf16(kf, qf[ch], sf, 0, 0, 0);
        }
        __builtin_amdgcn_s_setprio(0);

        // ---- online softmax (exp2 domain), defer-max THR=11
        float tm = sf[0];
        #pragma unroll
        for (int i = 1; i < 16; i++) tm = fmaxf(tm, sf[i]);
        tm = fmaxf(tm, __shfl_xor(tm, 32));
        if (__any(tm > mmax + 11.0f)) {
            float mn = fmaxf(mmax, tm);
            float corr = exp2f(mmax - mn);
            lsum *= corr;
            #pragma unroll
            for (int cb = 0; cb < 8; cb++) acc[cb] *= corr;
            mmax = mn;
        }
        #pragma unroll
        for (int i = 0; i < 16; i++) {
            sf[i] = exp2f(sf[i] - mmax);
            lsum += sf[i];
        }
        // pack P; lane holds P[q=m][kv=(reg&3)+8*(reg>>2)+4*hl]
        uint32_t pk0 = pkbf(sf[0], sf[1]),   pk1 = pkbf(sf[2], sf[3]);
        uint32_t pk2 = pkbf(sf[4], sf[5]),   pk3 = pkbf(sf[6], sf[7]);
        uint32_t pk4 = pkbf(sf[8], sf[9]),   pk5 = pkbf(sf[10], sf[11]);
        uint32_t pk6 = pkbf(sf[12], sf[13]), pk7 = pkbf(sf[14], sf[15]);
        uint2v r0 = __builtin_amdgcn_permlane32_swap(pk0, pk2, false, false);
        uint2v r1 = __builtin_amdgcn_permlane32_swap(pk1, pk3, false, false);
        uint2v r2 = __builtin_amdgcn_permlane32_swap(pk4, pk6, false, false);
        uint2v r3 = __builtin_amdgcn_permlane32_swap(pk5, pk7, false, false);
        uint4 u0; u0.x = r0[0]; u0.y = r1[0]; u0.z = r0[1]; u0.w = r1[1];
        uint4 u1; u1.x = r2[0]; u1.y = r3[0]; u1.z = r2[1]; u1.w = r3[1];
        bf16x8 pf0 = __builtin_bit_cast(bf16x8, u0);   // P^T[kv 0..15][q]
        bf16x8 pf1 = __builtin_bit_cast(bf16x8, u1);   // P^T[kv 16..31][q]

        // ---- out^T[c][q] += Vt . P^T
        __builtin_amdgcn_s_setprio(1);
        #pragma unroll
        for (int cb = 0; cb < 8; cb++) {
            int rowb = (cb * 4 + (m >> 3)) * 512 + (m & 7) * 16;
            bf16x8 v0 = *reinterpret_cast<const bf16x8*>(vb + rowb + hl * 128);
            acc[cb] = __builtin_amdgcn_mfma_f32_32x32x16_bf16(v0, pf0, acc[cb], 0, 0, 0);
            bf16x8 v1 = *reinterpret_cast<const bf16x8*>(vb + rowb + (2 + hl) * 128);
            acc[cb] = __builtin_amdgcn_mfma_f32_32x32x16_bf16(v1, pf1, acc[cb], 0, 0, 0);
        }
        __builtin_amdgcn_s_setprio(0);

        // publish stage(step+1); all reads of buf[cur] complete block-wide
        publish_barrier();
        if (step + 2 < 32) {                    // refill just-consumed buffers
            stageK(step + 2, cur);
            stageV(step + 2, cur);
        }
    }

    // ---- epilogue: per-q-row total lsum, write normalized partial
    lsum += __shfl_xor(lsum, 32);
    float inv = 1.0f / lsum;
    float wgt = lsum * exp2f(mmax);
    size_t qrow = (size_t)(q0 + m);
    if (h == 0) {
        #pragma unroll
        for (int cb = 0; cb < 8; cb++)
            #pragma unroll
            for (int q4 = 0; q4 < 4; q4++) {
                int c0i = cb * 32 + q4 * 8 + 4 * hl;
                float4 o;
                o.x = acc[cb][q4 * 4 + 0] * inv;
                o.y = acc[cb][q4 * 4 + 1] * inv;
                o.z = acc[cb][q4 * 4 + 2] * inv;
                o.w = acc[cb][q4 * 4 + 3] * inv;
                *reinterpret_cast<float4*>(out + qrow * 256 + c0i) = o;
            }
        if (hl == 0) ml[qrow] = wgt;
    } else {
        #pragma unroll
        for (int cb = 0; cb < 8; cb++)
            #pragma unroll
            for (int q4 = 0; q4 < 4; q4++) {
                int c0i = cb * 32 + q4 * 8 + 4 * hl;
                uint2 u;
                u.x = pkbf(acc[cb][q4 * 4 + 0] * inv, acc[cb][q4 * 4 + 1] * inv);
                u.y = pkbf(acc[cb][q4 * 4 + 2] * inv, acc[cb][q4 * 4 + 3] * inv);
                *reinterpret_cast<uint2*>(part1 + qrow * 256 + c0i) = u;
            }
        if (hl == 0) ml[BM_ + qrow] = wgt;
    }
}

// ---------------------------------------------------------------- kernel 5
// Merge halves (exact online-softmax combine) + LayerNorm + LeakyReLU.
// One wave per q-row; lane owns 4 channels.
__global__ void merge_ln_kernel(const unsigned short* __restrict__ part1,
                                const float* __restrict__ ml,
                                const float* __restrict__ gam,
                                const float* __restrict__ bet,
                                float* __restrict__ out) {
    int w = threadIdx.x >> 6, lane = threadIdx.x & 63;
    size_t row = (size_t)blockIdx.x * 4 + w;
    float w0 = ml[row], w1 = ml[BM_ + row];
    float rs = 1.0f / (w0 + w1);
    float4 o0 = *reinterpret_cast<float4*>(out + row * 256 + lane * 4);
    ushort4 p = *reinterpret_cast<const ushort4*>(part1 + row * 256 + lane * 4);
    float4 v;
    v.x = (w0 * o0.x + w1 * bf2f(p.x)) * rs;
    v.y = (w0 * o0.y + w1 * bf2f(p.y)) * rs;
    v.z = (w0 * o0.z + w1 * bf2f(p.z)) * rs;
    v.w = (w0 * o0.w + w1 * bf2f(p.w)) * rs;
    float s = v.x + v.y + v.z + v.w;
    float q = v.x * v.x + v.y * v.y + v.z * v.z + v.w * v.w;
    #pragma unroll
    for (int m = 1; m < 64; m <<= 1) { s += __shfl_xor(s, m); q += __shfl_xor(q, m); }
    float mu = s * (1.0f / 256.0f);
    float var = q * (1.0f / 256.0f) - mu * mu;
    float rstd = rsqrtf(var + 1e-5f);
    float4 gg = *reinterpret_cast<const float4*>(gam + lane * 4);
    float4 bb = *reinterpret_cast<const float4*>(bet + lane * 4);
    float4 o;
    o.x = (v.x - mu) * rstd * gg.x + bb.x;
    o.y = (v.y - mu) * rstd * gg.y + bb.y;
    o.z = (v.z - mu) * rstd * gg.z + bb.z;
    o.w = (v.w - mu) * rstd * gg.w + bb.w;
    o.x = o.x >= 0.f ? o.x : 0.01f * o.x;
    o.y = o.y >= 0.f ? o.y : 0.01f * o.y;
    o.z = o.z >= 0.f ? o.z : 0.01f * o.z;
    o.w = o.w >= 0.f ? o.w : 0.01f * o.w;
    *reinterpret_cast<float4*>(out + row * 256 + lane * 4) = o;
}

// ---------------------------------------------------------------- launcher
extern "C" void kernel_launch(void* const* d_in, const int* in_sizes, int n_in,
                              void* d_out, int out_size, void* d_ws, size_t ws_size,
                              hipStream_t stream) {
    const float* local_feat = (const float*)d_in[0];
    const float* adj_w    = (const float*)d_in[3];
    const float* affine_w = (const float*)d_in[4];
    const float* affine_b = (const float*)d_in[5];
    const float* ln_g     = (const float*)d_in[6];
    const float* ln_b     = (const float*)d_in[7];
    float* out = (float*)d_out;

    char* ws = (char*)d_ws;
    unsigned short* nf    = (unsigned short*)(ws);                 // 16 MiB
    unsigned short* q     = (unsigned short*)(ws + 16777216);      // 16 MiB
    unsigned short* vt    = (unsigned short*)(ws + 33554432);      // 16 MiB
    float*          norms = (float*)         (ws + 50331648);      // 128 KiB
    unsigned short* adjT5 = (unsigned short*)(ws + 50462720);      // 128 KiB
    unsigned short* affw  = (unsigned short*)(ws + 50593792);      // 128 KiB
    unsigned short* part1 = (unsigned short*)(ws + 50724864);      // 16 MiB  bf16 [BM][256]
    float*          ml    = (float*)         (ws + 67502080);      // 256 KiB f32  [2][BM]

    prep_weights<<<256, 256, 0, stream>>>(adj_w, affine_w, adjT5, affw);
    l2norm_kernel<<<BM_ / 4, 256, 0, stream>>>(local_feat, nf, norms);
    dual_gemm<<<BM_ / 128, 512, 0, stream>>>(nf, adjT5, affw, norms, affine_b, q, vt);
    flash_kernel<<<512, 256, 0, stream>>>(q, nf, vt, out, part1, ml);
    merge_ln_kernel<<<BM_ / 4, 256, 0, stream>>>(part1, ml, ln_g, ln_b, out);
}

// Round 8
// 136.984 us; speedup vs baseline: 1.7923x; 1.4069x over previous
//
#include <hip/hip_runtime.h>
#include <hip/hip_bf16.h>
#include <stdint.h>

// Shapes (fixed by the problem)
#define B_  16
#define M_  2048            // T*N
#define C_  256
#define BM_ 32768           // B_*M_

typedef __bf16 bf16x8 __attribute__((ext_vector_type(8)));
typedef __bf16 bf16x2 __attribute__((ext_vector_type(2)));
typedef float  f32x4  __attribute__((ext_vector_type(4)));
typedef float  f32x16 __attribute__((ext_vector_type(16)));
typedef unsigned int uint2v __attribute__((ext_vector_type(2)));

__device__ __forceinline__ unsigned short f2bf(float f) {
    uint32_t u = __builtin_bit_cast(uint32_t, f);
    u += 0x7fffu + ((u >> 16) & 1u);          // RNE
    return (unsigned short)(u >> 16);
}

__device__ __forceinline__ uint32_t pkbf(float a, float b) {
    bf16x2 t; t[0] = (__bf16)a; t[1] = (__bf16)b;   // compiler -> v_cvt_pk_bf16_f32
    return __builtin_bit_cast(uint32_t, t);
}

__device__ __forceinline__ float bf2f(unsigned short u) {
    return __builtin_bit_cast(float, ((uint32_t)u) << 16);
}

// async global->LDS, 16B/lane; LDS dest = wave-uniform base, HW adds lane*16
__device__ __forceinline__ void gload16(const void* g, void* l) {
    __builtin_amdgcn_global_load_lds(
        (const __attribute__((address_space(1))) void*)g,
        (__attribute__((address_space(3))) void*)l, 16, 0, 0);
}

// Explicit LDS-DMA publish: drain vmcnt BEFORE the barrier, fence scheduler.
__device__ __forceinline__ void publish_barrier() {
    asm volatile("s_waitcnt vmcnt(0)" ::: "memory");
    __builtin_amdgcn_sched_barrier(0);
    __syncthreads();
    __builtin_amdgcn_sched_barrier(0);
}

// ---------------------------------------------------------------- kernel 1
// adjT5 = 5*log2(e) * adj^T (logits in exp2 domain); affwB = bf16(affine_w)
__global__ void prep_weights(const float* __restrict__ adj,
                             const float* __restrict__ affw,
                             unsigned short* __restrict__ adjT5,
                             unsigned short* __restrict__ affwB) {
    int idx = blockIdx.x * 256 + threadIdx.x;   // 0..65535
    int d = idx >> 8, c = idx & 255;
    adjT5[d * 256 + c] = f2bf(7.2134752f * adj[c * 256 + d]);
    affwB[idx] = f2bf(affw[idx]);
}

// ---------------------------------------------------------------- kernel 2
__global__ void l2norm_kernel(const float* __restrict__ x,
                              unsigned short* __restrict__ nf,
                              float* __restrict__ norms) {
    int w = threadIdx.x >> 6, lane = threadIdx.x & 63;
    int row = blockIdx.x * 4 + w;
    const float4 v = *reinterpret_cast<const float4*>(x + (size_t)row * 256 + lane * 4);
    float ss = v.x * v.x + v.y * v.y + v.z * v.z + v.w * v.w;
    #pragma unroll
    for (int m = 1; m < 64; m <<= 1) ss += __shfl_xor(ss, m);
    float nrm = sqrtf(ss);
    float s = 1.0f / fmaxf(nrm, 1e-12f);
    ushort4 o;
    o.x = f2bf(v.x * s); o.y = f2bf(v.y * s); o.z = f2bf(v.z * s); o.w = f2bf(v.w * s);
    *reinterpret_cast<ushort4*>(nf + (size_t)row * 256 + lane * 4) = o;
    if (lane == 0) norms[row] = nrm;
}

// ---------------------------------------------------------------- kernel 3
// One pass over nf producing BOTH Q = nf@adjT5 (row-major) and V3 =
// norms*(nf@affw)+bias stored in FLASH-STAGING-LINEAR order:
// V3[kvblk][slot][8 ushorts], slot = (cb*2+j)*64 + hl*32 + (c&31), holding
// V[c = cb*32+(c&31)][kv = kvblk*32 + j*16 + hl*8 + e]. Flash then stages &
// reads V with fully-linear, conflict-free addresses.
__global__ __launch_bounds__(512, 2)
void dual_gemm(const unsigned short* __restrict__ A,
               const unsigned short* __restrict__ B1,
               const unsigned short* __restrict__ B2,
               const float* __restrict__ norms,
               const float* __restrict__ bias,
               unsigned short* __restrict__ outQ,
               unsigned short* __restrict__ outV3) {
    __shared__ unsigned short bb1[256 * 56];
    __shared__ unsigned short bb2[256 * 56];
    int tid = threadIdx.x;
    int w = tid >> 6, lane = tid & 63, g = lane >> 4, r = lane & 15;
    int m0 = blockIdx.x * 128;

    const f32x4 z = {0.f, 0.f, 0.f, 0.f};
    f32x4 accq[16], accv[16];
    #pragma unroll
    for (int i = 0; i < 16; i++) { accq[i] = z; accv[i] = z; }

    for (int dc = 0; dc < 8; dc++) {
        __syncthreads();
        #pragma unroll
        for (int it = 0; it < 2; it++) {
            int n = (w * 2 + it) * 16 + (lane >> 2);
            int t = lane & 3;
            *reinterpret_cast<uint4*>(&bb1[n * 56 + t * 8]) =
                *reinterpret_cast<const uint4*>(B1 + (size_t)n * 256 + dc * 32 + t * 8);
            *reinterpret_cast<uint4*>(&bb2[n * 56 + t * 8]) =
                *reinterpret_cast<const uint4*>(B2 + (size_t)n * 256 + dc * 32 + t * 8);
        }
        __syncthreads();
        bf16x8 af = *reinterpret_cast<const bf16x8*>(
            A + (size_t)(m0 + w * 16 + r) * 256 + dc * 32 + g * 8);
        #pragma unroll
        for (int nf16 = 0; nf16 < 16; nf16++) {
            bf16x8 b1f = *reinterpret_cast<const bf16x8*>(&bb1[(nf16 * 16 + r) * 56 + g * 8]);
            accq[nf16] = __builtin_amdgcn_mfma_f32_16x16x32_bf16(af, b1f, accq[nf16], 0, 0, 0);
            bf16x8 b2f = *reinterpret_cast<const bf16x8*>(&bb2[(nf16 * 16 + r) * 56 + g * 8]);
            accv[nf16] = __builtin_amdgcn_mfma_f32_16x16x32_bf16(af, b2f, accv[nf16], 0, 0, 0);
        }
    }
    // Q epilogue: row-major
    #pragma unroll
    for (int nf16 = 0; nf16 < 16; nf16++) {
        int n = nf16 * 16 + r;
        #pragma unroll
        for (int j = 0; j < 4; j++) {
            int m = m0 + w * 16 + g * 4 + j;
            outQ[(size_t)m * 256 + n] = f2bf(accq[nf16][j]);
        }
    }
    // V3 epilogue: staging-linear layout, * norms + bias
    int mm = m0 + w * 16 + g * 4;               // kv row of acc elem 0 (4-aligned)
    int kvblk = mm >> 5;
    int kv0 = mm & 31;
    int jj  = kv0 >> 4;                         // 16-kv half
    int hl2 = (kv0 >> 3) & 1;                   // 8-kv sub
    int e0  = kv0 & 7;                          // 0 or 4
    float4 nr = *reinterpret_cast<const float4*>(norms + mm);
    #pragma unroll
    for (int nf16 = 0; nf16 < 16; nf16++) {
        int n = nf16 * 16 + r;
        int cb = n >> 5, mrow = n & 31;
        int slot = (cb * 2 + jj) * 64 + hl2 * 32 + mrow;
        float bv = bias[n];
        ushort4 o;
        o.x = f2bf(accv[nf16][0] * nr.x + bv);
        o.y = f2bf(accv[nf16][1] * nr.y + bv);
        o.z = f2bf(accv[nf16][2] * nr.z + bv);
        o.w = f2bf(accv[nf16][3] * nr.w + bv);
        *reinterpret_cast<ushort4*>(outV3 + (size_t)kvblk * 8192 + slot * 8 + e0) = o;
    }
}

// ---------------------------------------------------------------- kernel 4
// Flash v9 (r5 base): 512 thr = 2 kv-groups x 4 waves; wave = 32 q rows via
// 32x32x16 MFMA. K double-buffered with r5's XOR-swizzled staging/reads;
// V double-buffered in STAGING-LINEAR layout (contiguous gload16 source,
// lane-linear conflict-free ds_read_b128 with imm offsets).
// Per-step order: QK -> softmax -> PV -> publish_barrier -> stage(step+2).
// Epilogue: bf16 in-LDS group merge + fused LayerNorm + LeakyReLU.
// LDS 129KB: group h at h*65536 {K0@0 K1@16K V0@32K V1@48K}; merge aliases
// group0 (64KB bf16 partials) + ml @131072 (1KB).
__global__ __launch_bounds__(512, 1)
void flash_kernel(const unsigned short* __restrict__ Q,
                  const unsigned short* __restrict__ K,
                  const unsigned short* __restrict__ V3,
                  const float* __restrict__ gam,
                  const float* __restrict__ bet,
                  float* __restrict__ out) {
    __shared__ __align__(16) char smem[132096];
    const int tid = threadIdx.x;
    const int w = tid >> 6, lane = tid & 63;
    const int wg = w & 3, h = w >> 2;           // q sub-block, kv group
    const int hl = lane >> 5, m = lane & 31;    // lane half, lane-in-half
    const int blk = blockIdx.x;
    const int b = (blk & 7) * 2 + (blk >> 7);   // XCD-pinned batch
    const int mblk = (blk >> 3) & 15;
    const int q0 = b * M_ + mblk * 128 + wg * 32;
    const int gtid = wg * 64 + lane;            // tid within group (0..255)

    char* gbase = smem + h * 65536;

    // Q fragments: B-operand; lane holds Q[q0+m][ch*16 + hl*8 ..+8]
    bf16x8 qf[16];
    #pragma unroll
    for (int ch = 0; ch < 16; ch++)
        qf[ch] = *reinterpret_cast<const bf16x8*>(
            Q + (size_t)(q0 + m) * 256 + ch * 16 + hl * 8);

    const f32x16 z16 = {0,0,0,0, 0,0,0,0, 0,0,0,0, 0,0,0,0};
    f32x16 acc[8];
    #pragma unroll
    for (int cb = 0; cb < 8; cb++) acc[cb] = z16;
    float mmax = 0.0f, lsum = 0.0f;             // exp2 domain

    const unsigned short* Kb = K + (size_t)(b * M_ + h * 1024) * 256;
    // V staging source: fully linear; per-thread base, +8192 ushorts/step
    const unsigned short* Vsrc =
        V3 + ((size_t)(b * 64 + h * 32) * 1024 + gtid) * 8;

    auto stageK = [&](int step, int buf) {
        char* kb = gbase + buf * 16384;
        #pragma unroll
        for (int it = 0; it < 4; it++) {
            int s = it * 256 + gtid;
            int n = s >> 5, t = s & 31;
            gload16(Kb + (size_t)(step * 32 + n) * 256 + ((t ^ (n & 7)) * 8),
                    kb + (it * 256 + wg * 64) * 16);
        }
    };
    auto stageV = [&](int step, int buf) {
        char* vb = gbase + 32768 + buf * 16384;
        const unsigned short* src = Vsrc + (size_t)step * 8192;
        #pragma unroll
        for (int it = 0; it < 4; it++) {
            gload16(src + it * 2048, vb + (it * 256 + wg * 64) * 16);
        }
    };

    stageK(0, 0); stageV(0, 0);
    publish_barrier();
    stageK(1, 1); stageV(1, 1);

    #pragma unroll 2
    for (int step = 0; step < 32; step++) {
        const int cur = step & 1;
        char* kb = gbase + cur * 16384;
        char* vb = gbase + 32768 + cur * 16384;

        // ---- S^T[32 kv][32 q] = K . Q^T
        f32x16 sf = z16;
        __builtin_amdgcn_s_setprio(1);
        #pragma unroll
        for (int ch = 0; ch < 16; ch++) {
            int slot = (ch * 2 + hl) ^ (m & 7);
            bf16x8 kf = *reinterpret_cast<const bf16x8*>(kb + m * 512 + slot * 16);
            sf = __builtin_amdgcn_mfma_f32_32x32x16_bf16(kf, qf[ch], sf, 0, 0, 0);
        }
        __builtin_amdgcn_s_setprio(0);

        // ---- online softmax (exp2 domain), defer-max THR=11
        float tm = sf[0];
        #pragma unroll
        for (int i = 1; i < 16; i++) tm = fmaxf(tm, sf[i]);
        tm = fmaxf(tm, __shfl_xor(tm, 32));
        if (__any(tm > mmax + 11.0f)) {
            float mn = fmaxf(mmax, tm);
            float corr = exp2f(mmax - mn);
            lsum *= corr;
            #pragma unroll
            for (int cb = 0; cb < 8; cb++) acc[cb] *= corr;
            mmax = mn;
        }
        #pragma unroll
        for (int i = 0; i < 16; i++) {
            sf[i] = exp2f(sf[i] - mmax);
            lsum += sf[i];
        }
        // pack P; lane holds P[q=m][kv=(reg&3)+8*(reg>>2)+4*hl]
        uint32_t pk0 = pkbf(sf[0], sf[1]),   pk1 = pkbf(sf[2], sf[3]);
        uint32_t pk2 = pkbf(sf[4], sf[5]),   pk3 = pkbf(sf[6], sf[7]);
        uint32_t pk4 = pkbf(sf[8], sf[9]),   pk5 = pkbf(sf[10], sf[11]);
        uint32_t pk6 = pkbf(sf[12], sf[13]), pk7 = pkbf(sf[14], sf[15]);
        uint2v r0 = __builtin_amdgcn_permlane32_swap(pk0, pk2, false, false);
        uint2v r1 = __builtin_amdgcn_permlane32_swap(pk1, pk3, false, false);
        uint2v r2 = __builtin_amdgcn_permlane32_swap(pk4, pk6, false, false);
        uint2v r3 = __builtin_amdgcn_permlane32_swap(pk5, pk7, false, false);
        uint4 u0; u0.x = r0[0]; u0.y = r1[0]; u0.z = r0[1]; u0.w = r1[1];
        uint4 u1; u1.x = r2[0]; u1.y = r3[0]; u1.z = r2[1]; u1.w = r3[1];
        bf16x8 pf0 = __builtin_bit_cast(bf16x8, u0);   // P^T[kv 0..15][q]
        bf16x8 pf1 = __builtin_bit_cast(bf16x8, u1);   // P^T[kv 16..31][q]

        // ---- out^T[c][q] += V . P^T  (linear, conflict-free V reads)
        __builtin_amdgcn_s_setprio(1);
        #pragma unroll
        for (int cb = 0; cb < 8; cb++) {
            bf16x8 v0 = *reinterpret_cast<const bf16x8*>(
                vb + lane * 16 + (cb * 2 + 0) * 1024);
            acc[cb] = __builtin_amdgcn_mfma_f32_32x32x16_bf16(v0, pf0, acc[cb], 0, 0, 0);
            bf16x8 v1 = *reinterpret_cast<const bf16x8*>(
                vb + lane * 16 + (cb * 2 + 1) * 1024);
            acc[cb] = __builtin_amdgcn_mfma_f32_32x32x16_bf16(v1, pf1, acc[cb], 0, 0, 0);
        }
        __builtin_amdgcn_s_setprio(0);

        // publish stage(step+1); all K/V reads of buf[cur] complete block-wide
        publish_barrier();
        if (step + 2 < 32) {                    // refill just-consumed buffers
            stageK(step + 2, cur);
            stageV(step + 2, cur);
        }
    }

    publish_barrier();                          // drain tail stages; alias LDS

    // ---- cross-half lsum; per-group weight
    lsum += __shfl_xor(lsum, 32);
    float inv = 1.0f / lsum;
    float wgt = lsum * exp2f(mmax);

    // ---- group merge through LDS (bf16 partials, 64KB @0 + ml @131072)
    unsigned short* mp = (unsigned short*)smem;
    float* mlp = (float*)(smem + 131072);
    if (h == 1) {
        #pragma unroll
        for (int cb = 0; cb < 8; cb++)
            #pragma unroll
            for (int q4 = 0; q4 < 4; q4++) {
                int c0i = cb * 32 + q4 * 8 + 4 * hl;
                uint2 u;
                u.x = pkbf(acc[cb][q4 * 4 + 0] * inv, acc[cb][q4 * 4 + 1] * inv);
                u.y = pkbf(acc[cb][q4 * 4 + 2] * inv, acc[cb][q4 * 4 + 3] * inv);
                *reinterpret_cast<uint2*>(mp + (size_t)wg * 8192 + m * 256 + c0i) = u;
            }
        if (hl == 0) mlp[wg * 32 + m] = wgt;
    }
    __syncthreads();
    if (h == 0) {
        float w1 = mlp[wg * 32 + m];
        float rsw = 1.0f / (wgt + w1);
        float c0 = wgt * rsw * inv;             // applies inv to h=0 raw acc
        float c1 = w1 * rsw;
        float s = 0.0f, ssq = 0.0f;
        #pragma unroll
        for (int cb = 0; cb < 8; cb++)
            #pragma unroll
            for (int q4 = 0; q4 < 4; q4++) {
                int c0i = cb * 32 + q4 * 8 + 4 * hl;
                uint2 u = *reinterpret_cast<const uint2*>(
                    mp + (size_t)wg * 8192 + m * 256 + c0i);
                float p0 = bf2f((unsigned short)(u.x & 0xffff));
                float p1 = bf2f((unsigned short)(u.x >> 16));
                float p2 = bf2f((unsigned short)(u.y & 0xffff));
                float p3 = bf2f((unsigned short)(u.y >> 16));
                float v0 = acc[cb][q4 * 4 + 0] * c0 + p0 * c1;
                float v1 = acc[cb][q4 * 4 + 1] * c0 + p1 * c1;
                float v2 = acc[cb][q4 * 4 + 2] * c0 + p2 * c1;
                float v3 = acc[cb][q4 * 4 + 3] * c0 + p3 * c1;
                acc[cb][q4 * 4 + 0] = v0; acc[cb][q4 * 4 + 1] = v1;
                acc[cb][q4 * 4 + 2] = v2; acc[cb][q4 * 4 + 3] = v3;
                s += (v0 + v1) + (v2 + v3);
                ssq += v0 * v0 + v1 * v1 + v2 * v2 + v3 * v3;
            }
        s   += __shfl_xor(s, 32);
        ssq += __shfl_xor(ssq, 32);
        float mu = s * (1.0f / 256.0f);
        float var = ssq * (1.0f / 256.0f) - mu * mu;
        float rstd = rsqrtf(var + 1e-5f);
        size_t rowoff = (size_t)(q0 + m) * 256;
        #pragma unroll
        for (int cb = 0; cb < 8; cb++)
            #pragma unroll
            for (int q4 = 0; q4 < 4; q4++) {
                int c0i = cb * 32 + q4 * 8 + 4 * hl;
                float4 gg = *reinterpret_cast<const float4*>(gam + c0i);
                float4 bb = *reinterpret_cast<const float4*>(bet + c0i);
                float4 o;
                o.x = (acc[cb][q4 * 4 + 0] - mu) * rstd * gg.x + bb.x;
                o.y = (acc[cb][q4 * 4 + 1] - mu) * rstd * gg.y + bb.y;
                o.z = (acc[cb][q4 * 4 + 2] - mu) * rstd * gg.z + bb.z;
                o.w = (acc[cb][q4 * 4 + 3] - mu) * rstd * gg.w + bb.w;
                o.x = o.x >= 0.f ? o.x : 0.01f * o.x;
                o.y = o.y >= 0.f ? o.y : 0.01f * o.y;
                o.z = o.z >= 0.f ? o.z : 0.01f * o.z;
                o.w = o.w >= 0.f ? o.w : 0.01f * o.w;
                *reinterpret_cast<float4*>(out + rowoff + c0i) = o;
            }
    }
}

// ---------------------------------------------------------------- launcher
extern "C" void kernel_launch(void* const* d_in, const int* in_sizes, int n_in,
                              void* d_out, int out_size, void* d_ws, size_t ws_size,
                              hipStream_t stream) {
    const float* local_feat = (const float*)d_in[0];
    const float* adj_w    = (const float*)d_in[3];
    const float* affine_w = (const float*)d_in[4];
    const float* affine_b = (const float*)d_in[5];
    const float* ln_g     = (const float*)d_in[6];
    const float* ln_b     = (const float*)d_in[7];
    float* out = (float*)d_out;

    char* ws = (char*)d_ws;
    unsigned short* nf    = (unsigned short*)(ws);                 // 16 MiB
    unsigned short* q     = (unsigned short*)(ws + 16777216);      // 16 MiB
    unsigned short* v3    = (unsigned short*)(ws + 33554432);      // 16 MiB
    float*          norms = (float*)         (ws + 50331648);      // 128 KiB
    unsigned short* adjT5 = (unsigned short*)(ws + 50462720);      // 128 KiB
    unsigned short* affw  = (unsigned short*)(ws + 50593792);      // 128 KiB

    prep_weights<<<256, 256, 0, stream>>>(adj_w, affine_w, adjT5, affw);
    l2norm_kernel<<<BM_ / 4, 256, 0, stream>>>(local_feat, nf, norms);
    dual_gemm<<<BM_ / 128, 512, 0, stream>>>(nf, adjT5, affw, norms, affine_b, q, v3);
    flash_kernel<<<256, 512, 0, stream>>>(q, nf, v3, ln_g, ln_b, out);
}

// Round 9
// 131.168 us; speedup vs baseline: 1.8718x; 1.0443x over previous
//
#include <hip/hip_runtime.h>
#include <hip/hip_bf16.h>
#include <stdint.h>

// Shapes (fixed by the problem)
#define B_  16
#define M_  2048            // T*N
#define C_  256
#define BM_ 32768           // B_*M_

typedef __bf16 bf16x8 __attribute__((ext_vector_type(8)));
typedef __bf16 bf16x2 __attribute__((ext_vector_type(2)));
typedef float  f32x4  __attribute__((ext_vector_type(4)));
typedef float  f32x16 __attribute__((ext_vector_type(16)));
typedef unsigned int uint2v __attribute__((ext_vector_type(2)));

__device__ __forceinline__ unsigned short f2bf(float f) {
    uint32_t u = __builtin_bit_cast(uint32_t, f);
    u += 0x7fffu + ((u >> 16) & 1u);          // RNE
    return (unsigned short)(u >> 16);
}

__device__ __forceinline__ uint32_t pkbf(float a, float b) {
    bf16x2 t; t[0] = (__bf16)a; t[1] = (__bf16)b;   // compiler -> v_cvt_pk_bf16_f32
    return __builtin_bit_cast(uint32_t, t);
}

__device__ __forceinline__ float bf2f(unsigned short u) {
    return __builtin_bit_cast(float, ((uint32_t)u) << 16);
}

// async global->LDS, 16B/lane; LDS dest = wave-uniform base, HW adds lane*16
__device__ __forceinline__ void gload16(const void* g, void* l) {
    __builtin_amdgcn_global_load_lds(
        (const __attribute__((address_space(1))) void*)g,
        (__attribute__((address_space(3))) void*)l, 16, 0, 0);
}

// Explicit LDS-DMA publish: drain vmcnt BEFORE the barrier, fence scheduler.
__device__ __forceinline__ void publish_barrier() {
    asm volatile("s_waitcnt vmcnt(0)" ::: "memory");
    __builtin_amdgcn_sched_barrier(0);
    __syncthreads();
    __builtin_amdgcn_sched_barrier(0);
}

// ---------------------------------------------------------------- kernel 1
// adjT5 = 5*log2(e) * adj^T (logits in exp2 domain); affwB = bf16(affine_w)
__global__ void prep_weights(const float* __restrict__ adj,
                             const float* __restrict__ affw,
                             unsigned short* __restrict__ adjT5,
                             unsigned short* __restrict__ affwB) {
    int idx = blockIdx.x * 256 + threadIdx.x;   // 0..65535
    int d = idx >> 8, c = idx & 255;
    adjT5[d * 256 + c] = f2bf(7.2134752f * adj[c * 256 + d]);
    affwB[idx] = f2bf(affw[idx]);
}

// ---------------------------------------------------------------- kernel 2
__global__ void l2norm_kernel(const float* __restrict__ x,
                              unsigned short* __restrict__ nf,
                              float* __restrict__ norms) {
    int w = threadIdx.x >> 6, lane = threadIdx.x & 63;
    int row = blockIdx.x * 4 + w;
    const float4 v = *reinterpret_cast<const float4*>(x + (size_t)row * 256 + lane * 4);
    float ss = v.x * v.x + v.y * v.y + v.z * v.z + v.w * v.w;
    #pragma unroll
    for (int m = 1; m < 64; m <<= 1) ss += __shfl_xor(ss, m);
    float nrm = sqrtf(ss);
    float s = 1.0f / fmaxf(nrm, 1e-12f);
    ushort4 o;
    o.x = f2bf(v.x * s); o.y = f2bf(v.y * s); o.z = f2bf(v.z * s); o.w = f2bf(v.w * s);
    *reinterpret_cast<ushort4*>(nf + (size_t)row * 256 + lane * 4) = o;
    if (lane == 0) norms[row] = nrm;
}

// ---------------------------------------------------------------- kernel 3
// One pass over nf producing:
//  Q  = nf@adjT5, row-major
//  V3 = norms*(nf@affw)+bias, flash-staging-linear (as r8)
//  K3 = nf repacked to flash-staging-linear K layout:
//       K3[kvblk][ch*512 + (khl*32+m)*8 + e] = nf[kvblk*32+m][ch*16+khl*8+e]
//       (the af fragment we already loaded is exactly one such 16B chunk)
__global__ __launch_bounds__(512, 2)
void dual_gemm(const unsigned short* __restrict__ A,
               const unsigned short* __restrict__ B1,
               const unsigned short* __restrict__ B2,
               const float* __restrict__ norms,
               const float* __restrict__ bias,
               unsigned short* __restrict__ outQ,
               unsigned short* __restrict__ outV3,
               unsigned short* __restrict__ outK3) {
    __shared__ unsigned short bb1[256 * 56];
    __shared__ unsigned short bb2[256 * 56];
    int tid = threadIdx.x;
    int w = tid >> 6, lane = tid & 63, g = lane >> 4, r = lane & 15;
    int m0 = blockIdx.x * 128;

    const f32x4 z = {0.f, 0.f, 0.f, 0.f};
    f32x4 accq[16], accv[16];
    #pragma unroll
    for (int i = 0; i < 16; i++) { accq[i] = z; accv[i] = z; }

    int row = m0 + w * 16 + r;
    int kvblk_r = row >> 5, mrow = row & 31;

    for (int dc = 0; dc < 8; dc++) {
        __syncthreads();
        #pragma unroll
        for (int it = 0; it < 2; it++) {
            int n = (w * 2 + it) * 16 + (lane >> 2);
            int t = lane & 3;
            *reinterpret_cast<uint4*>(&bb1[n * 56 + t * 8]) =
                *reinterpret_cast<const uint4*>(B1 + (size_t)n * 256 + dc * 32 + t * 8);
            *reinterpret_cast<uint4*>(&bb2[n * 56 + t * 8]) =
                *reinterpret_cast<const uint4*>(B2 + (size_t)n * 256 + dc * 32 + t * 8);
        }
        __syncthreads();
        bf16x8 af = *reinterpret_cast<const bf16x8*>(
            A + (size_t)row * 256 + dc * 32 + g * 8);
        // K3 store: c-range = dc*32+g*8 -> ch = dc*2+(g>>1), khl = g&1
        {
            int ch = dc * 2 + (g >> 1);
            int khl = g & 1;
            *reinterpret_cast<bf16x8*>(
                outK3 + (size_t)kvblk_r * 8192 + ch * 512 + (khl * 32 + mrow) * 8) = af;
        }
        #pragma unroll
        for (int nf16 = 0; nf16 < 16; nf16++) {
            bf16x8 b1f = *reinterpret_cast<const bf16x8*>(&bb1[(nf16 * 16 + r) * 56 + g * 8]);
            accq[nf16] = __builtin_amdgcn_mfma_f32_16x16x32_bf16(af, b1f, accq[nf16], 0, 0, 0);
            bf16x8 b2f = *reinterpret_cast<const bf16x8*>(&bb2[(nf16 * 16 + r) * 56 + g * 8]);
            accv[nf16] = __builtin_amdgcn_mfma_f32_16x16x32_bf16(af, b2f, accv[nf16], 0, 0, 0);
        }
    }
    // Q epilogue: row-major
    #pragma unroll
    for (int nf16 = 0; nf16 < 16; nf16++) {
        int n = nf16 * 16 + r;
        #pragma unroll
        for (int j = 0; j < 4; j++) {
            int m = m0 + w * 16 + g * 4 + j;
            outQ[(size_t)m * 256 + n] = f2bf(accq[nf16][j]);
        }
    }
    // V3 epilogue: staging-linear layout, * norms + bias
    int mm = m0 + w * 16 + g * 4;               // kv row of acc elem 0 (4-aligned)
    int kvblk = mm >> 5;
    int kv0 = mm & 31;
    int jj  = kv0 >> 4;                         // 16-kv half
    int hl2 = (kv0 >> 3) & 1;                   // 8-kv sub
    int e0  = kv0 & 7;                          // 0 or 4
    float4 nr = *reinterpret_cast<const float4*>(norms + mm);
    #pragma unroll
    for (int nf16 = 0; nf16 < 16; nf16++) {
        int n = nf16 * 16 + r;
        int cb = n >> 5, mr2 = n & 31;
        int slot = (cb * 2 + jj) * 64 + hl2 * 32 + mr2;
        float bv = bias[n];
        ushort4 o;
        o.x = f2bf(accv[nf16][0] * nr.x + bv);
        o.y = f2bf(accv[nf16][1] * nr.y + bv);
        o.z = f2bf(accv[nf16][2] * nr.z + bv);
        o.w = f2bf(accv[nf16][3] * nr.w + bv);
        *reinterpret_cast<ushort4*>(outV3 + (size_t)kvblk * 8192 + slot * 8 + e0) = o;
    }
}

// ---------------------------------------------------------------- kernel 4
// Flash v10 (r8 base): 512 thr = 2 kv-groups x 4 waves; wave = 32 q rows
// via 32x32x16 MFMA. K AND V both double-buffered in STAGING-LINEAR layout
// (contiguous gload16 sources, lane-linear conflict-free ds_read_b128 with
// imm offsets, zero swizzle VALU). Rolled main loop (register pressure).
// Per-step order: QK -> softmax -> PV -> publish_barrier -> stage(step+2).
// Epilogue: bf16 in-LDS group merge + fused LayerNorm + LeakyReLU.
// LDS 129KB: group h at h*65536 {K0@0 K1@16K V0@32K V1@48K}; merge aliases
// group0 (64KB bf16 partials) + ml @131072 (1KB).
__global__ __launch_bounds__(512, 1)
void flash_kernel(const unsigned short* __restrict__ Q,
                  const unsigned short* __restrict__ K3,
                  const unsigned short* __restrict__ V3,
                  const float* __restrict__ gam,
                  const float* __restrict__ bet,
                  float* __restrict__ out) {
    __shared__ __align__(16) char smem[132096];
    const int tid = threadIdx.x;
    const int w = tid >> 6, lane = tid & 63;
    const int wg = w & 3, h = w >> 2;           // q sub-block, kv group
    const int hl = lane >> 5, m = lane & 31;    // lane half, lane-in-half
    const int blk = blockIdx.x;
    const int b = (blk & 7) * 2 + (blk >> 7);   // XCD-pinned batch
    const int mblk = (blk >> 3) & 15;
    const int q0 = b * M_ + mblk * 128 + wg * 32;
    const int gtid = wg * 64 + lane;            // tid within group (0..255)

    char* gbase = smem + h * 65536;

    // Q fragments: B-operand; lane holds Q[q0+m][ch*16 + hl*8 ..+8]
    bf16x8 qf[16];
    #pragma unroll
    for (int ch = 0; ch < 16; ch++)
        qf[ch] = *reinterpret_cast<const bf16x8*>(
            Q + (size_t)(q0 + m) * 256 + ch * 16 + hl * 8);

    const f32x16 z16 = {0,0,0,0, 0,0,0,0, 0,0,0,0, 0,0,0,0};
    f32x16 acc[8];
    #pragma unroll
    for (int cb = 0; cb < 8; cb++) acc[cb] = z16;
    float mmax = 0.0f, lsum = 0.0f;             // exp2 domain

    // staging sources: fully linear; per-thread base, +8192 ushorts/step
    const unsigned short* Ksrc =
        K3 + ((size_t)(b * 64 + h * 32) * 1024 + gtid) * 8;
    const unsigned short* Vsrc =
        V3 + ((size_t)(b * 64 + h * 32) * 1024 + gtid) * 8;

    auto stageK = [&](int step, int buf) {
        char* kb = gbase + buf * 16384;
        const unsigned short* src = Ksrc + (size_t)step * 8192;
        #pragma unroll
        for (int it = 0; it < 4; it++)
            gload16(src + it * 2048, kb + (it * 256 + wg * 64) * 16);
    };
    auto stageV = [&](int step, int buf) {
        char* vb = gbase + 32768 + buf * 16384;
        const unsigned short* src = Vsrc + (size_t)step * 8192;
        #pragma unroll
        for (int it = 0; it < 4; it++)
            gload16(src + it * 2048, vb + (it * 256 + wg * 64) * 16);
    };

    stageK(0, 0); stageV(0, 0);
    publish_barrier();
    stageK(1, 1); stageV(1, 1);

    for (int step = 0; step < 32; step++) {
        const int cur = step & 1;
        const char* kbl = gbase + cur * 16384 + lane * 16;
        const char* vbl = gbase + 32768 + cur * 16384 + lane * 16;

        // ---- S^T[32 kv][32 q] = K . Q^T  (linear conflict-free kf reads)
        f32x16 sf = z16;
        __builtin_amdgcn_s_setprio(1);
        #pragma unroll
        for (int ch = 0; ch < 16; ch++) {
            bf16x8 kf = *reinterpret_cast<const bf16x8*>(kbl + ch * 1024);
            sf = __builtin_amdgcn_mfma_f32_32x32x16_bf16(kf, qf[ch], sf, 0, 0, 0);
        }
        __builtin_amdgcn_s_setprio(0);

        // ---- online softmax (exp2 domain), defer-max THR=11
        float tm = sf[0];
        #pragma unroll
        for (int i = 1; i < 16; i++) tm = fmaxf(tm, sf[i]);
        tm = fmaxf(tm, __shfl_xor(tm, 32));
        if (__any(tm > mmax + 11.0f)) {
            float mn = fmaxf(mmax, tm);
            float corr = exp2f(mmax - mn);
            lsum *= corr;
            #pragma unroll
            for (int cb = 0; cb < 8; cb++) acc[cb] *= corr;
            mmax = mn;
        }
        #pragma unroll
        for (int i = 0; i < 16; i++) {
            sf[i] = exp2f(sf[i] - mmax);
            lsum += sf[i];
        }
        // pack P; lane holds P[q=m][kv=(reg&3)+8*(reg>>2)+4*hl]
        uint32_t pk0 = pkbf(sf[0], sf[1]),   pk1 = pkbf(sf[2], sf[3]);
        uint32_t pk2 = pkbf(sf[4], sf[5]),   pk3 = pkbf(sf[6], sf[7]);
        uint32_t pk4 = pkbf(sf[8], sf[9]),   pk5 = pkbf(sf[10], sf[11]);
        uint32_t pk6 = pkbf(sf[12], sf[13]), pk7 = pkbf(sf[14], sf[15]);
        uint2v r0 = __builtin_amdgcn_permlane32_swap(pk0, pk2, false, false);
        uint2v r1 = __builtin_amdgcn_permlane32_swap(pk1, pk3, false, false);
        uint2v r2 = __builtin_amdgcn_permlane32_swap(pk4, pk6, false, false);
        uint2v r3 = __builtin_amdgcn_permlane32_swap(pk5, pk7, false, false);
        uint4 u0; u0.x = r0[0]; u0.y = r1[0]; u0.z = r0[1]; u0.w = r1[1];
        uint4 u1; u1.x = r2[0]; u1.y = r3[0]; u1.z = r2[1]; u1.w = r3[1];
        bf16x8 pf0 = __builtin_bit_cast(bf16x8, u0);   // P^T[kv 0..15][q]
        bf16x8 pf1 = __builtin_bit_cast(bf16x8, u1);   // P^T[kv 16..31][q]

        // ---- out^T[c][q] += V . P^T  (linear, conflict-free V reads)
        __builtin_amdgcn_s_setprio(1);
        #pragma unroll
        for (int cb = 0; cb < 8; cb++) {
            bf16x8 v0 = *reinterpret_cast<const bf16x8*>(vbl + (cb * 2 + 0) * 1024);
            acc[cb] = __builtin_amdgcn_mfma_f32_32x32x16_bf16(v0, pf0, acc[cb], 0, 0, 0);
            bf16x8 v1 = *reinterpret_cast<const bf16x8*>(vbl + (cb * 2 + 1) * 1024);
            acc[cb] = __builtin_amdgcn_mfma_f32_32x32x16_bf16(v1, pf1, acc[cb], 0, 0, 0);
        }
        __builtin_amdgcn_s_setprio(0);

        // publish stage(step+1); all K/V reads of buf[cur] complete block-wide
        publish_barrier();
        if (step + 2 < 32) {                    // refill just-consumed buffers
            stageK(step + 2, cur);
            stageV(step + 2, cur);
        }
    }

    publish_barrier();                          // drain tail stages; alias LDS

    // ---- cross-half lsum; per-group weight
    lsum += __shfl_xor(lsum, 32);
    float inv = 1.0f / lsum;
    float wgt = lsum * exp2f(mmax);

    // ---- group merge through LDS (bf16 partials, 64KB @0 + ml @131072)
    unsigned short* mp = (unsigned short*)smem;
    float* mlp = (float*)(smem + 131072);
    if (h == 1) {
        #pragma unroll
        for (int cb = 0; cb < 8; cb++)
            #pragma unroll
            for (int q4 = 0; q4 < 4; q4++) {
                int c0i = cb * 32 + q4 * 8 + 4 * hl;
                uint2 u;
                u.x = pkbf(acc[cb][q4 * 4 + 0] * inv, acc[cb][q4 * 4 + 1] * inv);
                u.y = pkbf(acc[cb][q4 * 4 + 2] * inv, acc[cb][q4 * 4 + 3] * inv);
                *reinterpret_cast<uint2*>(mp + (size_t)wg * 8192 + m * 256 + c0i) = u;
            }
        if (hl == 0) mlp[wg * 32 + m] = wgt;
    }
    __syncthreads();
    if (h == 0) {
        float w1 = mlp[wg * 32 + m];
        float rsw = 1.0f / (wgt + w1);
        float c0 = wgt * rsw * inv;             // applies inv to h=0 raw acc
        float c1 = w1 * rsw;
        float s = 0.0f, ssq = 0.0f;
        #pragma unroll
        for (int cb = 0; cb < 8; cb++)
            #pragma unroll
            for (int q4 = 0; q4 < 4; q4++) {
                int c0i = cb * 32 + q4 * 8 + 4 * hl;
                uint2 u = *reinterpret_cast<const uint2*>(
                    mp + (size_t)wg * 8192 + m * 256 + c0i);
                float p0 = bf2f((unsigned short)(u.x & 0xffff));
                float p1 = bf2f((unsigned short)(u.x >> 16));
                float p2 = bf2f((unsigned short)(u.y & 0xffff));
                float p3 = bf2f((unsigned short)(u.y >> 16));
                float v0 = acc[cb][q4 * 4 + 0] * c0 + p0 * c1;
                float v1 = acc[cb][q4 * 4 + 1] * c0 + p1 * c1;
                float v2 = acc[cb][q4 * 4 + 2] * c0 + p2 * c1;
                float v3 = acc[cb][q4 * 4 + 3] * c0 + p3 * c1;
                acc[cb][q4 * 4 + 0] = v0; acc[cb][q4 * 4 + 1] = v1;
                acc[cb][q4 * 4 + 2] = v2; acc[cb][q4 * 4 + 3] = v3;
                s += (v0 + v1) + (v2 + v3);
                ssq += v0 * v0 + v1 * v1 + v2 * v2 + v3 * v3;
            }
        s   += __shfl_xor(s, 32);
        ssq += __shfl_xor(ssq, 32);
        float mu = s * (1.0f / 256.0f);
        float var = ssq * (1.0f / 256.0f) - mu * mu;
        float rstd = rsqrtf(var + 1e-5f);
        size_t rowoff = (size_t)(q0 + m) * 256;
        #pragma unroll
        for (int cb = 0; cb < 8; cb++)
            #pragma unroll
            for (int q4 = 0; q4 < 4; q4++) {
                int c0i = cb * 32 + q4 * 8 + 4 * hl;
                float4 gg = *reinterpret_cast<const float4*>(gam + c0i);
                float4 bb = *reinterpret_cast<const float4*>(bet + c0i);
                float4 o;
                o.x = (acc[cb][q4 * 4 + 0] - mu) * rstd * gg.x + bb.x;
                o.y = (acc[cb][q4 * 4 + 1] - mu) * rstd * gg.y + bb.y;
                o.z = (acc[cb][q4 * 4 + 2] - mu) * rstd * gg.z + bb.z;
                o.w = (acc[cb][q4 * 4 + 3] - mu) * rstd * gg.w + bb.w;
                o.x = o.x >= 0.f ? o.x : 0.01f * o.x;
                o.y = o.y >= 0.f ? o.y : 0.01f * o.y;
                o.z = o.z >= 0.f ? o.z : 0.01f * o.z;
                o.w = o.w >= 0.f ? o.w : 0.01f * o.w;
                *reinterpret_cast<float4*>(out + rowoff + c0i) = o;
            }
    }
}

// ---------------------------------------------------------------- launcher
extern "C" void kernel_launch(void* const* d_in, const int* in_sizes, int n_in,
                              void* d_out, int out_size, void* d_ws, size_t ws_size,
                              hipStream_t stream) {
    const float* local_feat = (const float*)d_in[0];
    const float* adj_w    = (const float*)d_in[3];
    const float* affine_w = (const float*)d_in[4];
    const float* affine_b = (const float*)d_in[5];
    const float* ln_g     = (const float*)d_in[6];
    const float* ln_b     = (const float*)d_in[7];
    float* out = (float*)d_out;

    char* ws = (char*)d_ws;
    unsigned short* nf    = (unsigned short*)(ws);                 // 16 MiB
    unsigned short* q     = (unsigned short*)(ws + 16777216);      // 16 MiB
    unsigned short* v3    = (unsigned short*)(ws + 33554432);      // 16 MiB
    float*          norms = (float*)         (ws + 50331648);      // 128 KiB
    unsigned short* adjT5 = (unsigned short*)(ws + 50462720);      // 128 KiB
    unsigned short* affw  = (unsigned short*)(ws + 50593792);      // 128 KiB
    unsigned short* k3    = (unsigned short*)(ws + 50724864);      // 16 MiB

    prep_weights<<<256, 256, 0, stream>>>(adj_w, affine_w, adjT5, affw);
    l2norm_kernel<<<BM_ / 4, 256, 0, stream>>>(local_feat, nf, norms);
    dual_gemm<<<BM_ / 128, 512, 0, stream>>>(nf, adjT5, affw, norms, affine_b, q, v3, k3);
    flash_kernel<<<256, 512, 0, stream>>>(q, k3, v3, ln_g, ln_b, out);
}